// Round 15
// baseline (271.561 us; speedup 1.0000x reference)
//
#include <hip/hip_runtime.h>
#include <stdint.h>
#include <math.h>

#define IN_C 256
#define HID 128
#define OUT_C 64
#define NB 256        // dst buckets
#define CHUNK 8192    // edges per chunk in hist/scatter phases

typedef __attribute__((ext_vector_type(8))) short bf16x8;
typedef __attribute__((ext_vector_type(4))) float f32x4;

__device__ inline ushort f2bf(float f) {
    uint u = __float_as_uint(f);
    u += 0x7fff + ((u >> 16) & 1);           // RNE
    return (ushort)(u >> 16);
}
__device__ inline void split2(float f, ushort& h, ushort& l) {
    h = f2bf(f);
    float fh = __uint_as_float(((uint)h) << 16);
    l = f2bf(f - fh);
}

// ---------------------------------------------------------------------------
// prepA: fused {histA | wsplit W1 | wsplit W2} via blockIdx branch.
// ---------------------------------------------------------------------------
__global__ __launch_bounds__(256) void prepA_kernel(const int* __restrict__ ei,
                                                    int* __restrict__ hist,
                                                    int e, int n, unsigned bmag,
                                                    const float* __restrict__ W1,
                                                    const float* __restrict__ Wmu,
                                                    const float* __restrict__ Wls,
                                                    ushort* __restrict__ wt1_hi,
                                                    ushort* __restrict__ wt1_lo,
                                                    ushort* __restrict__ wt2_hi,
                                                    ushort* __restrict__ wt2_lo,
                                                    int nchunks) {
    __shared__ int h[NB];
    const int b = blockIdx.x;
    const int t = threadIdx.x;
    if (b < nchunks) {
        h[t] = 0;
        __syncthreads();
        const int base = b * CHUNK;
        #pragma unroll
        for (int i = 0; i < CHUNK / 256; ++i) {
            int j = base + t + i * 256;
            int d = -1;
            if (j < e) d = ei[e + j];
            else if (j < e + n) d = j - e;          // self-loop
            if (d >= 0) atomicAdd(&h[__umulhi((unsigned)d, bmag)], 1);
        }
        __syncthreads();
        hist[b * NB + t] = h[t];
    } else if (b < nchunks + 128) {
        int idx = (b - nchunks) * 256 + t;          // [0, 32768)
        int k = idx >> 7, c = idx & 127;
        ushort hh, ll;
        split2(W1[k * 128 + c], hh, ll);
        wt1_hi[(size_t)c * IN_C + k] = hh;
        wt1_lo[(size_t)c * IN_C + k] = ll;
    } else {
        int idx = (b - nchunks - 128) * 256 + t;    // [0, 16384)
        int k = idx >> 7, c = idx & 127;
        float w = (c < 64) ? Wmu[k * 64 + c] : Wls[k * 64 + (c - 64)];
        ushort hh, ll;
        split2(w, hh, ll);
        wt2_hi[(size_t)c * HID + k] = hh;
        wt2_lo[(size_t)c * HID + k] = ll;
    }
}

// ---------------------------------------------------------------------------
// scans
// ---------------------------------------------------------------------------
__global__ __launch_bounds__(256) void scanB1_kernel(int* __restrict__ hist,
                                                     int* __restrict__ totals,
                                                     int nchunks) {
    __shared__ int buf[256];
    const int b = blockIdx.x;
    const int t = threadIdx.x;
    int running = 0;
    for (int base = 0; base < nchunks; base += 256) {
        int idx = base + t;
        int v = (idx < nchunks) ? hist[idx * NB + b] : 0;
        buf[t] = v;
        __syncthreads();
        for (int g = 1; g < 256; g <<= 1) {
            int add = (t >= g) ? buf[t - g] : 0;
            __syncthreads();
            buf[t] += add;
            __syncthreads();
        }
        if (idx < nchunks) hist[idx * NB + b] = running + buf[t] - v;
        running += buf[255];
        __syncthreads();
    }
    if (t == 0) totals[b] = running;
}

__global__ __launch_bounds__(256) void scanB2_kernel(const int* __restrict__ totals,
                                                     int* __restrict__ bbase) {
    __shared__ int buf[256];
    const int t = threadIdx.x;
    int v = totals[t];
    buf[t] = v;
    __syncthreads();
    for (int g = 1; g < 256; g <<= 1) {
        int add = (t >= g) ? buf[t - g] : 0;
        __syncthreads();
        buf[t] += add;
        __syncthreads();
    }
    bbase[t] = buf[t] - v;
    if (t == 255) bbase[256] = buf[255];
}

// ---------------------------------------------------------------------------
// LDS-staged MFMA GEMM body (round-8 proven).
// ---------------------------------------------------------------------------
template <int K, bool SCALE>
__device__ __forceinline__ void gemm_body(const float* __restrict__ X,
                                          const ushort* __restrict__ wt_hi,
                                          const ushort* __restrict__ wt_lo,
                                          ushort* __restrict__ O, int n,
                                          const float* __restrict__ rowscale,
                                          int blk, char* smem) {
    ushort (*xs_hi)[40] = (ushort(*)[40])(smem);            // 64 x 40 x 2B
    ushort (*xs_lo)[40] = (ushort(*)[40])(smem + 5120);
    ushort (*ws_hi)[40] = (ushort(*)[40])(smem + 10240);    // 128 x 40 x 2B
    ushort (*ws_lo)[40] = (ushort(*)[40])(smem + 20480);
    const int tid = threadIdx.x;
    const int wid = tid >> 6;
    const int lane = tid & 63;
    const int arow = lane & 15;
    const int kgrp = lane >> 4;
    const int wr = wid >> 1;
    const int wc = wid & 1;
    const int row0 = blk * 64;

    const ushort* wsrc = (tid < 128) ? wt_hi : wt_lo;
    const int wcidx = tid & 127;

    f32x4 acc[2][4];
    #pragma unroll
    for (int rt = 0; rt < 2; ++rt)
        #pragma unroll
        for (int ct = 0; ct < 4; ++ct) acc[rt][ct] = (f32x4){0.f, 0.f, 0.f, 0.f};

    for (int k0 = 0; k0 < K; k0 += 32) {
        float4 xv[2];
        #pragma unroll
        for (int i = 0; i < 2; ++i) {
            int idx = tid + i * 256;
            int r = idx >> 3, kq = (idx & 7) * 4;
            int row = row0 + r;
            xv[i] = (row < n) ? *(const float4*)&X[(size_t)row * K + k0 + kq]
                              : make_float4(0.f, 0.f, 0.f, 0.f);
        }
        uint4 wv[4];
        #pragma unroll
        for (int q = 0; q < 4; ++q)
            wv[q] = *(const uint4*)&wsrc[(size_t)wcidx * K + k0 + q * 8];
        #pragma unroll
        for (int i = 0; i < 2; ++i) {
            int idx = tid + i * 256;
            int r = idx >> 3, kq = (idx & 7) * 4;
            ushort4 h4, l4;
            split2(xv[i].x, h4.x, l4.x);
            split2(xv[i].y, h4.y, l4.y);
            split2(xv[i].z, h4.z, l4.z);
            split2(xv[i].w, h4.w, l4.w);
            *(ushort4*)&xs_hi[r][kq] = h4;
            *(ushort4*)&xs_lo[r][kq] = l4;
        }
        {
            ushort (*wdst)[40] = (tid < 128) ? ws_hi : ws_lo;
            #pragma unroll
            for (int q = 0; q < 4; ++q)
                *(uint4*)&wdst[wcidx][q * 8] = wv[q];
        }
        __syncthreads();
        bf16x8 a_hi[2], a_lo[2];
        #pragma unroll
        for (int rt = 0; rt < 2; ++rt) {
            a_hi[rt] = *(const bf16x8*)&xs_hi[wr * 32 + rt * 16 + arow][kgrp * 8];
            a_lo[rt] = *(const bf16x8*)&xs_lo[wr * 32 + rt * 16 + arow][kgrp * 8];
        }
        #pragma unroll
        for (int ct = 0; ct < 4; ++ct) {
            int col = wc * 64 + ct * 16 + arow;
            bf16x8 b_hi = *(const bf16x8*)&ws_hi[col][kgrp * 8];
            bf16x8 b_lo = *(const bf16x8*)&ws_lo[col][kgrp * 8];
            #pragma unroll
            for (int rt = 0; rt < 2; ++rt) {
                acc[rt][ct] = __builtin_amdgcn_mfma_f32_16x16x32_bf16(a_hi[rt], b_hi, acc[rt][ct], 0, 0, 0);
                acc[rt][ct] = __builtin_amdgcn_mfma_f32_16x16x32_bf16(a_hi[rt], b_lo, acc[rt][ct], 0, 0, 0);
                acc[rt][ct] = __builtin_amdgcn_mfma_f32_16x16x32_bf16(a_lo[rt], b_hi, acc[rt][ct], 0, 0, 0);
            }
        }
        __syncthreads();
    }
    #pragma unroll
    for (int rt = 0; rt < 2; ++rt)
        #pragma unroll
        for (int ct = 0; ct < 4; ++ct)
            #pragma unroll
            for (int r = 0; r < 4; ++r) {
                int row = row0 + wr * 32 + rt * 16 + kgrp * 4 + r;
                int col = wc * 64 + ct * 16 + arow;
                if (row < n) {
                    float v = acc[rt][ct][r];
                    if (SCALE) v *= rowscale[row];
                    O[(size_t)row * 128 + col] = f2bf(v);
                }
            }
}

__global__ __launch_bounds__(256) void gemm1_kernel(const float* __restrict__ X,
                                                    const ushort* __restrict__ wt_hi,
                                                    const ushort* __restrict__ wt_lo,
                                                    ushort* __restrict__ O, int n) {
    __shared__ char smem[30720];
    gemm_body<IN_C, false>(X, wt_hi, wt_lo, O, n, nullptr, blockIdx.x, smem);
}

__global__ __launch_bounds__(256) void gemm2_kernel(const float* __restrict__ X,
                                                    const ushort* __restrict__ wt_hi,
                                                    const ushort* __restrict__ wt_lo,
                                                    ushort* __restrict__ O, int n,
                                                    const float* __restrict__ dinv) {
    __shared__ char smem[30720];
    gemm_body<HID, true>(X, wt_hi, wt_lo, O, n, dinv, blockIdx.x, smem);
}

// ---------------------------------------------------------------------------
// scatterC: LDS-cursor bucket scatter, 1 KB LDS. dst-in-bucket packed into
// bits 17..24 of ptmp.x (src fits 17 bits; nn <= 224 fits 8 bits).
// ---------------------------------------------------------------------------
__global__ __launch_bounds__(256) void scatterC_kernel(const int* __restrict__ ei,
                                                       const float* __restrict__ ew,
                                                       const int* __restrict__ hist,
                                                       const int* __restrict__ bbase,
                                                       float2* __restrict__ ptmp,
                                                       int e, int n, unsigned bmag) {
    __shared__ int cur[NB];
    const int t = threadIdx.x;
    cur[t] = bbase[t] + hist[blockIdx.x * NB + t];
    __syncthreads();
    const int base = blockIdx.x * CHUNK;
    #pragma unroll
    for (int i = 0; i < CHUNK / 256; ++i) {
        int j = base + t + i * 256;
        if (j < e + n) {
            int d, s;
            float w;
            if (j < e) { d = ei[e + j]; s = ei[j]; w = ew[j]; }
            else       { d = j - e;     s = d;     w = 1.0f;  }
            unsigned bkt = __umulhi((unsigned)d, bmag);
            int lo = ((int)bkt * n + NB - 1) / NB;
            int pos = atomicAdd(&cur[bkt], 1);
            ptmp[pos] = make_float2(__int_as_float(s | ((d - lo) << 17)), w);
        }
    }
}

// ---------------------------------------------------------------------------
// bucketD: per-bucket CSR finalize (dinv[dst] folded into val) + tail:
// scale this bucket's h0 rows by dinv (dinv[src] fold).
// ---------------------------------------------------------------------------
__global__ __launch_bounds__(256) void bucketD_kernel(const float2* __restrict__ ptmp,
                                                      const int* __restrict__ bbase,
                                                      float2* __restrict__ pairs,
                                                      int* __restrict__ rowptr,
                                                      float* __restrict__ dinv,
                                                      ushort* __restrict__ h0,
                                                      int n, int nnz) {
    const int b = blockIdx.x;
    const int t = threadIdx.x;
    const int lo = (b * n + NB - 1) / NB;
    const int hi = ((b + 1) * n + NB - 1) / NB;
    const int nn = hi - lo;                       // <= 224
    __shared__ int   cnt[224];
    __shared__ float deg[224];
    __shared__ float dv[224];
    __shared__ int   cur2[224];
    __shared__ int   sb[256];
    if (t < nn) { cnt[t] = 0; deg[t] = 0.f; }
    __syncthreads();
    const int s0 = bbase[b], s1 = bbase[b + 1];
    for (int k = s0 + t; k < s1; k += 256) {
        float2 p = ptmp[k];
        int dl = (__float_as_int(p.x) >> 17) & 0xFF;
        atomicAdd(&cnt[dl], 1);
        atomicAdd(&deg[dl], p.y);
    }
    __syncthreads();
    int v = (t < nn) ? cnt[t] : 0;
    sb[t] = v;
    __syncthreads();
    for (int g = 1; g < 256; g <<= 1) {
        int add = (t >= g) ? sb[t - g] : 0;
        __syncthreads();
        sb[t] += add;
        __syncthreads();
    }
    if (t < nn) {
        int excl = sb[t] - v;
        int node = lo + t;
        float di = rsqrtf(deg[t]);
        rowptr[node] = s0 + excl;
        dinv[node] = di;
        dv[t] = di;
        cur2[t] = s0 + excl;
    }
    __syncthreads();
    for (int k = s0 + t; k < s1; k += 256) {
        float2 p = ptmp[k];
        int bits = __float_as_int(p.x);
        int dl = (bits >> 17) & 0xFF;
        int pos = atomicAdd(&cur2[dl], 1);
        pairs[pos] = make_float2(__int_as_float(bits & 0x1FFFF), p.y * dv[dl]);
    }
    if (b == NB - 1 && t == 0) rowptr[n] = nnz;
    // ---- tail: h0 rows [lo,hi) *= dinv ----
    {
        const int l = t & 63;
        for (int r = t >> 6; r < nn; r += 4) {
            float s = dv[r];
            uint* rowp = (uint*)&h0[(size_t)(lo + r) * 128];
            uint u = rowp[l];
            float a = __uint_as_float(u << 16) * s;
            float c = __uint_as_float(u & 0xffff0000u) * s;
            rowp[l] = ((uint)f2bf(c) << 16) | (uint)f2bf(a);
        }
    }
}

// ---------------------------------------------------------------------------
// Column-quarter aggregation: grid = 4 quarters x bpq blocks (quarter-major
// so each quarter's 3.2 MB slice of src is L2-resident during its phase).
// Block = 16 nodes x 16-lane groups; group g walks node's edge list for
// quarter q (16 uints = 32 cols). No cross-lane reduce; per-edge gather is
// one 64B line. 32 gathers in flight per wave.
// ---------------------------------------------------------------------------
template <bool IS1>
__global__ __launch_bounds__(256) void aggq_kernel(const int* __restrict__ rowptr,
                                                   const float2* __restrict__ pairs,
                                                   const uint* __restrict__ src,
                                                   const float* __restrict__ b1,
                                                   const float* __restrict__ bmu,
                                                   const float* __restrict__ bls,
                                                   float* __restrict__ out,
                                                   int n, int bpq) {
    const int t = threadIdx.x;
    const int g = t >> 4;            // node group 0..15
    const int c = t & 15;            // uint within quarter
    const int q = blockIdx.x / bpq;  // quarter 0..3 (phase-major dispatch)
    const int nb = blockIdx.x - q * bpq;
    const int node = nb * 16 + g;
    if (node >= n) return;
    int j = rowptr[node];
    const int end = rowptr[node + 1];
    const uint* sq = src + q * 16 + c;
    float2 acc = make_float2(0.f, 0.f);
    for (; j + 7 < end; j += 8) {
        float2 p0 = pairs[j],     p1 = pairs[j + 1], p2 = pairs[j + 2], p3 = pairs[j + 3];
        float2 p4 = pairs[j + 4], p5 = pairs[j + 5], p6 = pairs[j + 6], p7 = pairs[j + 7];
        uint u0 = sq[(size_t)__float_as_int(p0.x) * 64];
        uint u1 = sq[(size_t)__float_as_int(p1.x) * 64];
        uint u2 = sq[(size_t)__float_as_int(p2.x) * 64];
        uint u3 = sq[(size_t)__float_as_int(p3.x) * 64];
        uint u4 = sq[(size_t)__float_as_int(p4.x) * 64];
        uint u5 = sq[(size_t)__float_as_int(p5.x) * 64];
        uint u6 = sq[(size_t)__float_as_int(p6.x) * 64];
        uint u7 = sq[(size_t)__float_as_int(p7.x) * 64];
        acc.x += p0.y * __uint_as_float(u0 << 16);
        acc.y += p0.y * __uint_as_float(u0 & 0xffff0000u);
        acc.x += p1.y * __uint_as_float(u1 << 16);
        acc.y += p1.y * __uint_as_float(u1 & 0xffff0000u);
        acc.x += p2.y * __uint_as_float(u2 << 16);
        acc.y += p2.y * __uint_as_float(u2 & 0xffff0000u);
        acc.x += p3.y * __uint_as_float(u3 << 16);
        acc.y += p3.y * __uint_as_float(u3 & 0xffff0000u);
        acc.x += p4.y * __uint_as_float(u4 << 16);
        acc.y += p4.y * __uint_as_float(u4 & 0xffff0000u);
        acc.x += p5.y * __uint_as_float(u5 << 16);
        acc.y += p5.y * __uint_as_float(u5 & 0xffff0000u);
        acc.x += p6.y * __uint_as_float(u6 << 16);
        acc.y += p6.y * __uint_as_float(u6 & 0xffff0000u);
        acc.x += p7.y * __uint_as_float(u7 << 16);
        acc.y += p7.y * __uint_as_float(u7 & 0xffff0000u);
    }
    for (; j + 1 < end; j += 2) {
        float2 p0 = pairs[j], p1 = pairs[j + 1];
        uint u0 = sq[(size_t)__float_as_int(p0.x) * 64];
        uint u1 = sq[(size_t)__float_as_int(p1.x) * 64];
        acc.x += p0.y * __uint_as_float(u0 << 16) + p1.y * __uint_as_float(u1 << 16);
        acc.y += p0.y * __uint_as_float(u0 & 0xffff0000u) + p1.y * __uint_as_float(u1 & 0xffff0000u);
    }
    if (j < end) {
        float2 p0 = pairs[j];
        uint u0 = sq[(size_t)__float_as_int(p0.x) * 64];
        acc.x += p0.y * __uint_as_float(u0 << 16);
        acc.y += p0.y * __uint_as_float(u0 & 0xffff0000u);
    }
    const int ci = q * 32 + 2 * c;
    if (IS1) {
        acc.x += b1[ci];
        acc.y += b1[ci + 1];
        acc.x = acc.x > 0.f ? acc.x : expm1f(acc.x);
        acc.y = acc.y > 0.f ? acc.y : expm1f(acc.y);
        *(float2*)&out[(size_t)node * 128 + ci] = acc;
    } else {
        if (ci < 64) {
            acc.x += bmu[ci];
            acc.y += bmu[ci + 1];
            *(float2*)&out[(size_t)node * 64 + ci] = acc;
        } else {
            acc.x += bls[ci - 64];
            acc.y += bls[ci - 63];
            *(float2*)&out[(size_t)n * 64 + (size_t)node * 64 + (ci - 64)] = acc;
        }
    }
}

// ---------------------------------------------------------------------------

extern "C" void kernel_launch(void* const* d_in, const int* in_sizes, int n_in,
                              void* d_out, int out_size, void* d_ws, size_t ws_size,
                              hipStream_t stream) {
    const float* x   = (const float*)d_in[0];
    const int*   ei  = (const int*)d_in[1];
    const float* ew  = (const float*)d_in[2];
    const float* W1  = (const float*)d_in[3];
    const float* b1  = (const float*)d_in[4];
    const float* Wmu = (const float*)d_in[5];
    const float* bmu = (const float*)d_in[6];
    const float* Wls = (const float*)d_in[7];
    const float* bls = (const float*)d_in[8];
    float*       out = (float*)d_out;

    const int n = in_sizes[0] / IN_C;     // 50000
    const int e = in_sizes[2];            // 1600000
    const int nnz = e + n;
    const int nchunks = (nnz + CHUNK - 1) / CHUNK;
    const int gblocks = (n + 63) / 64;
    const int bpq = (n + 15) / 16;        // agg blocks per quarter
    const unsigned bmag = (unsigned)(((unsigned long long)NB << 32) / (unsigned)n + 1);

    char* ws = (char*)d_ws;
    size_t off = 0;
    auto alloc = [&](size_t bytes) -> void* {
        void* p = ws + off;
        off = (off + bytes + 255) & ~(size_t)255;
        return p;
    };
    int*    hist   = (int*)   alloc((size_t)nchunks * NB * 4);
    int*    totals = (int*)   alloc(NB * 4);
    int*    bbase  = (int*)   alloc((NB + 1) * 4);
    int*    rowptr = (int*)   alloc((size_t)(n + 1) * 4);
    float*  dinv   = (float*) alloc((size_t)n * 4);
    float2* pairs  = (float2*)alloc((size_t)nnz * 8);
    float2* ptmp   = (float2*)alloc((size_t)nnz * 8);
    ushort* wt1_hi = (ushort*)alloc((size_t)128 * IN_C * 2);
    ushort* wt1_lo = (ushort*)alloc((size_t)128 * IN_C * 2);
    ushort* wt2_hi = (ushort*)alloc((size_t)128 * HID * 2);
    ushort* wt2_lo = (ushort*)alloc((size_t)128 * HID * 2);
    ushort* h0     = (ushort*)alloc((size_t)n * 128 * 2);   // bf16; hcat reuses
    ushort* hcat   = h0;                                    // dead after agg1
    (void)ws_size;
    float* hbuf = out;   // layer-1 activations (fp32) live in d_out

    prepA_kernel<<<nchunks + 192, 256, 0, stream>>>(ei, hist, e, n, bmag,
                                                    W1, Wmu, Wls,
                                                    wt1_hi, wt1_lo, wt2_hi, wt2_lo, nchunks);
    scanB1_kernel<<<NB, 256, 0, stream>>>(hist, totals, nchunks);
    scanB2_kernel<<<1, 256, 0, stream>>>(totals, bbase);
    gemm1_kernel<<<gblocks, 256, 0, stream>>>(x, wt1_hi, wt1_lo, h0, n);
    scatterC_kernel<<<nchunks, 256, 0, stream>>>(ei, ew, hist, bbase, ptmp, e, n, bmag);
    bucketD_kernel<<<NB, 256, 0, stream>>>(ptmp, bbase, pairs, rowptr, dinv, h0, n, nnz);
    aggq_kernel<true><<<4 * bpq, 256, 0, stream>>>(rowptr, pairs, (const uint*)h0,
                                                   b1, nullptr, nullptr, hbuf, n, bpq);
    gemm2_kernel<<<gblocks, 256, 0, stream>>>(hbuf, wt2_hi, wt2_lo, hcat, n, dinv);
    aggq_kernel<false><<<4 * bpq, 256, 0, stream>>>(rowptr, pairs, (const uint*)hcat,
                                                    nullptr, bmu, bls, out, n, bpq);
}

// Round 16
// 216.487 us; speedup vs baseline: 1.2544x; 1.2544x over previous
//
#include <hip/hip_runtime.h>
#include <stdint.h>
#include <math.h>

#define IN_C 256
#define HID 128
#define OUT_C 64
#define NB 256        // dst buckets
#define CHUNK 8192    // edges per chunk in hist/scatter phases

typedef __attribute__((ext_vector_type(8))) short bf16x8;
typedef __attribute__((ext_vector_type(4))) float f32x4;

__device__ inline ushort f2bf(float f) {
    uint u = __float_as_uint(f);
    u += 0x7fff + ((u >> 16) & 1);           // RNE
    return (ushort)(u >> 16);
}
__device__ inline void split2(float f, ushort& h, ushort& l) {
    h = f2bf(f);
    float fh = __uint_as_float(((uint)h) << 16);
    l = f2bf(f - fh);
}

// ---------------------------------------------------------------------------
// prepA: fused {histA | wsplit W1 | wsplit W2} via blockIdx branch.
// ---------------------------------------------------------------------------
__global__ __launch_bounds__(256) void prepA_kernel(const int* __restrict__ ei,
                                                    int* __restrict__ hist,
                                                    int e, int n, unsigned bmag,
                                                    const float* __restrict__ W1,
                                                    const float* __restrict__ Wmu,
                                                    const float* __restrict__ Wls,
                                                    ushort* __restrict__ wt1_hi,
                                                    ushort* __restrict__ wt1_lo,
                                                    ushort* __restrict__ wt2_hi,
                                                    ushort* __restrict__ wt2_lo,
                                                    int nchunks) {
    __shared__ int h[NB];
    const int b = blockIdx.x;
    const int t = threadIdx.x;
    if (b < nchunks) {
        h[t] = 0;
        __syncthreads();
        const int base = b * CHUNK;
        #pragma unroll
        for (int i = 0; i < CHUNK / 256; ++i) {
            int j = base + t + i * 256;
            int d = -1;
            if (j < e) d = ei[e + j];
            else if (j < e + n) d = j - e;          // self-loop
            if (d >= 0) atomicAdd(&h[__umulhi((unsigned)d, bmag)], 1);
        }
        __syncthreads();
        hist[b * NB + t] = h[t];
    } else if (b < nchunks + 128) {
        int idx = (b - nchunks) * 256 + t;          // [0, 32768)
        int k = idx >> 7, c = idx & 127;
        ushort hh, ll;
        split2(W1[k * 128 + c], hh, ll);
        wt1_hi[(size_t)c * IN_C + k] = hh;
        wt1_lo[(size_t)c * IN_C + k] = ll;
    } else {
        int idx = (b - nchunks - 128) * 256 + t;    // [0, 16384)
        int k = idx >> 7, c = idx & 127;
        float w = (c < 64) ? Wmu[k * 64 + c] : Wls[k * 64 + (c - 64)];
        ushort hh, ll;
        split2(w, hh, ll);
        wt2_hi[(size_t)c * HID + k] = hh;
        wt2_lo[(size_t)c * HID + k] = ll;
    }
}

// ---------------------------------------------------------------------------
// scans
// ---------------------------------------------------------------------------
__global__ __launch_bounds__(256) void scanB1_kernel(int* __restrict__ hist,
                                                     int* __restrict__ totals,
                                                     int nchunks) {
    __shared__ int buf[256];
    const int b = blockIdx.x;
    const int t = threadIdx.x;
    int running = 0;
    for (int base = 0; base < nchunks; base += 256) {
        int idx = base + t;
        int v = (idx < nchunks) ? hist[idx * NB + b] : 0;
        buf[t] = v;
        __syncthreads();
        for (int g = 1; g < 256; g <<= 1) {
            int add = (t >= g) ? buf[t - g] : 0;
            __syncthreads();
            buf[t] += add;
            __syncthreads();
        }
        if (idx < nchunks) hist[idx * NB + b] = running + buf[t] - v;
        running += buf[255];
        __syncthreads();
    }
    if (t == 0) totals[b] = running;
}

__global__ __launch_bounds__(256) void scanB2_kernel(const int* __restrict__ totals,
                                                     int* __restrict__ bbase) {
    __shared__ int buf[256];
    const int t = threadIdx.x;
    int v = totals[t];
    buf[t] = v;
    __syncthreads();
    for (int g = 1; g < 256; g <<= 1) {
        int add = (t >= g) ? buf[t - g] : 0;
        __syncthreads();
        buf[t] += add;
        __syncthreads();
    }
    bbase[t] = buf[t] - v;
    if (t == 255) bbase[256] = buf[255];
}

// ---------------------------------------------------------------------------
// LDS-staged MFMA GEMM body (round-8 proven).
// ---------------------------------------------------------------------------
template <int K, bool SCALE>
__device__ __forceinline__ void gemm_body(const float* __restrict__ X,
                                          const ushort* __restrict__ wt_hi,
                                          const ushort* __restrict__ wt_lo,
                                          ushort* __restrict__ O, int n,
                                          const float* __restrict__ rowscale,
                                          int blk, char* smem) {
    ushort (*xs_hi)[40] = (ushort(*)[40])(smem);            // 64 x 40 x 2B
    ushort (*xs_lo)[40] = (ushort(*)[40])(smem + 5120);
    ushort (*ws_hi)[40] = (ushort(*)[40])(smem + 10240);    // 128 x 40 x 2B
    ushort (*ws_lo)[40] = (ushort(*)[40])(smem + 20480);
    const int tid = threadIdx.x;
    const int wid = tid >> 6;
    const int lane = tid & 63;
    const int arow = lane & 15;
    const int kgrp = lane >> 4;
    const int wr = wid >> 1;
    const int wc = wid & 1;
    const int row0 = blk * 64;

    const ushort* wsrc = (tid < 128) ? wt_hi : wt_lo;
    const int wcidx = tid & 127;

    f32x4 acc[2][4];
    #pragma unroll
    for (int rt = 0; rt < 2; ++rt)
        #pragma unroll
        for (int ct = 0; ct < 4; ++ct) acc[rt][ct] = (f32x4){0.f, 0.f, 0.f, 0.f};

    for (int k0 = 0; k0 < K; k0 += 32) {
        float4 xv[2];
        #pragma unroll
        for (int i = 0; i < 2; ++i) {
            int idx = tid + i * 256;
            int r = idx >> 3, kq = (idx & 7) * 4;
            int row = row0 + r;
            xv[i] = (row < n) ? *(const float4*)&X[(size_t)row * K + k0 + kq]
                              : make_float4(0.f, 0.f, 0.f, 0.f);
        }
        uint4 wv[4];
        #pragma unroll
        for (int q = 0; q < 4; ++q)
            wv[q] = *(const uint4*)&wsrc[(size_t)wcidx * K + k0 + q * 8];
        #pragma unroll
        for (int i = 0; i < 2; ++i) {
            int idx = tid + i * 256;
            int r = idx >> 3, kq = (idx & 7) * 4;
            ushort4 h4, l4;
            split2(xv[i].x, h4.x, l4.x);
            split2(xv[i].y, h4.y, l4.y);
            split2(xv[i].z, h4.z, l4.z);
            split2(xv[i].w, h4.w, l4.w);
            *(ushort4*)&xs_hi[r][kq] = h4;
            *(ushort4*)&xs_lo[r][kq] = l4;
        }
        {
            ushort (*wdst)[40] = (tid < 128) ? ws_hi : ws_lo;
            #pragma unroll
            for (int q = 0; q < 4; ++q)
                *(uint4*)&wdst[wcidx][q * 8] = wv[q];
        }
        __syncthreads();
        bf16x8 a_hi[2], a_lo[2];
        #pragma unroll
        for (int rt = 0; rt < 2; ++rt) {
            a_hi[rt] = *(const bf16x8*)&xs_hi[wr * 32 + rt * 16 + arow][kgrp * 8];
            a_lo[rt] = *(const bf16x8*)&xs_lo[wr * 32 + rt * 16 + arow][kgrp * 8];
        }
        #pragma unroll
        for (int ct = 0; ct < 4; ++ct) {
            int col = wc * 64 + ct * 16 + arow;
            bf16x8 b_hi = *(const bf16x8*)&ws_hi[col][kgrp * 8];
            bf16x8 b_lo = *(const bf16x8*)&ws_lo[col][kgrp * 8];
            #pragma unroll
            for (int rt = 0; rt < 2; ++rt) {
                acc[rt][ct] = __builtin_amdgcn_mfma_f32_16x16x32_bf16(a_hi[rt], b_hi, acc[rt][ct], 0, 0, 0);
                acc[rt][ct] = __builtin_amdgcn_mfma_f32_16x16x32_bf16(a_hi[rt], b_lo, acc[rt][ct], 0, 0, 0);
                acc[rt][ct] = __builtin_amdgcn_mfma_f32_16x16x32_bf16(a_lo[rt], b_hi, acc[rt][ct], 0, 0, 0);
            }
        }
        __syncthreads();
    }
    #pragma unroll
    for (int rt = 0; rt < 2; ++rt)
        #pragma unroll
        for (int ct = 0; ct < 4; ++ct)
            #pragma unroll
            for (int r = 0; r < 4; ++r) {
                int row = row0 + wr * 32 + rt * 16 + kgrp * 4 + r;
                int col = wc * 64 + ct * 16 + arow;
                if (row < n) {
                    float v = acc[rt][ct][r];
                    if (SCALE) v *= rowscale[row];
                    O[(size_t)row * 128 + col] = f2bf(v);
                }
            }
}

__global__ __launch_bounds__(256) void gemm1_kernel(const float* __restrict__ X,
                                                    const ushort* __restrict__ wt_hi,
                                                    const ushort* __restrict__ wt_lo,
                                                    ushort* __restrict__ O, int n) {
    __shared__ char smem[30720];
    gemm_body<IN_C, false>(X, wt_hi, wt_lo, O, n, nullptr, blockIdx.x, smem);
}

__global__ __launch_bounds__(256) void gemm2_kernel(const float* __restrict__ X,
                                                    const ushort* __restrict__ wt_hi,
                                                    const ushort* __restrict__ wt_lo,
                                                    ushort* __restrict__ O, int n,
                                                    const float* __restrict__ dinv) {
    __shared__ char smem[30720];
    gemm_body<HID, true>(X, wt_hi, wt_lo, O, n, dinv, blockIdx.x, smem);
}

// ---------------------------------------------------------------------------
// scatterC: LDS-cursor bucket scatter, 1 KB LDS. dst-in-bucket packed into
// bits 17..24 of ptmp.x (src fits 17 bits; nn <= 224 fits 8 bits).
// ---------------------------------------------------------------------------
__global__ __launch_bounds__(256) void scatterC_kernel(const int* __restrict__ ei,
                                                       const float* __restrict__ ew,
                                                       const int* __restrict__ hist,
                                                       const int* __restrict__ bbase,
                                                       float2* __restrict__ ptmp,
                                                       int e, int n, unsigned bmag) {
    __shared__ int cur[NB];
    const int t = threadIdx.x;
    cur[t] = bbase[t] + hist[blockIdx.x * NB + t];
    __syncthreads();
    const int base = blockIdx.x * CHUNK;
    #pragma unroll
    for (int i = 0; i < CHUNK / 256; ++i) {
        int j = base + t + i * 256;
        if (j < e + n) {
            int d, s;
            float w;
            if (j < e) { d = ei[e + j]; s = ei[j]; w = ew[j]; }
            else       { d = j - e;     s = d;     w = 1.0f;  }
            unsigned bkt = __umulhi((unsigned)d, bmag);
            int lo = ((int)bkt * n + NB - 1) / NB;
            int pos = atomicAdd(&cur[bkt], 1);
            ptmp[pos] = make_float2(__int_as_float(s | ((d - lo) << 17)), w);
        }
    }
}

// ---------------------------------------------------------------------------
// bucketD: per-bucket CSR finalize (dinv[dst] folded into val) + tail:
// scale this bucket's h0 rows by dinv (dinv[src] fold).
// ---------------------------------------------------------------------------
__global__ __launch_bounds__(256) void bucketD_kernel(const float2* __restrict__ ptmp,
                                                      const int* __restrict__ bbase,
                                                      float2* __restrict__ pairs,
                                                      int* __restrict__ rowptr,
                                                      float* __restrict__ dinv,
                                                      ushort* __restrict__ h0,
                                                      int n, int nnz) {
    const int b = blockIdx.x;
    const int t = threadIdx.x;
    const int lo = (b * n + NB - 1) / NB;
    const int hi = ((b + 1) * n + NB - 1) / NB;
    const int nn = hi - lo;                       // <= 224
    __shared__ int   cnt[224];
    __shared__ float deg[224];
    __shared__ float dv[224];
    __shared__ int   cur2[224];
    __shared__ int   sb[256];
    if (t < nn) { cnt[t] = 0; deg[t] = 0.f; }
    __syncthreads();
    const int s0 = bbase[b], s1 = bbase[b + 1];
    for (int k = s0 + t; k < s1; k += 256) {
        float2 p = ptmp[k];
        int dl = (__float_as_int(p.x) >> 17) & 0xFF;
        atomicAdd(&cnt[dl], 1);
        atomicAdd(&deg[dl], p.y);
    }
    __syncthreads();
    int v = (t < nn) ? cnt[t] : 0;
    sb[t] = v;
    __syncthreads();
    for (int g = 1; g < 256; g <<= 1) {
        int add = (t >= g) ? sb[t - g] : 0;
        __syncthreads();
        sb[t] += add;
        __syncthreads();
    }
    if (t < nn) {
        int excl = sb[t] - v;
        int node = lo + t;
        float di = rsqrtf(deg[t]);
        rowptr[node] = s0 + excl;
        dinv[node] = di;
        dv[t] = di;
        cur2[t] = s0 + excl;
    }
    __syncthreads();
    for (int k = s0 + t; k < s1; k += 256) {
        float2 p = ptmp[k];
        int bits = __float_as_int(p.x);
        int dl = (bits >> 17) & 0xFF;
        int pos = atomicAdd(&cur2[dl], 1);
        pairs[pos] = make_float2(__int_as_float(bits & 0x1FFFF), p.y * dv[dl]);
    }
    if (b == NB - 1 && t == 0) rowptr[n] = nnz;
    // ---- tail: h0 rows [lo,hi) *= dinv ----
    {
        const int l = t & 63;
        for (int r = t >> 6; r < nn; r += 4) {
            float s = dv[r];
            uint* rowp = (uint*)&h0[(size_t)(lo + r) * 128];
            uint u = rowp[l];
            float a = __uint_as_float(u << 16) * s;
            float c = __uint_as_float(u & 0xffff0000u) * s;
            rowp[l] = ((uint)f2bf(c) << 16) | (uint)f2bf(a);
        }
    }
}

// ---------------------------------------------------------------------------
// Aggregation over bf16 rows: one wave per node, 1 uint (2 bf16) per lane.
// Simple 8-deep edge unroll. Row bounds via readfirstlane -> pairs walk
// scalarizes to s_load (proven: VGPR 28->16, agg 60->52 us).
// ---------------------------------------------------------------------------
#define AGG_GATHER(P, U) \
    uint U = src[(size_t)__float_as_int((P).x) * 64 + lane];
#define AGG_FMA(P, U) \
    acc.x += (P).y * __uint_as_float((U) << 16); \
    acc.y += (P).y * __uint_as_float((U) & 0xffff0000u);

__device__ inline float2 agg_row(const int* __restrict__ rowptr,
                                 const float2* __restrict__ pairs,
                                 const uint* __restrict__ src, int node, int lane) {
    const int start = __builtin_amdgcn_readfirstlane(rowptr[node]);
    const int end = __builtin_amdgcn_readfirstlane(rowptr[node + 1]);
    float2 acc = make_float2(0.f, 0.f);
    int j = start;
    for (; j + 7 < end; j += 8) {
        float2 p0 = pairs[j],     p1 = pairs[j + 1], p2 = pairs[j + 2], p3 = pairs[j + 3];
        float2 p4 = pairs[j + 4], p5 = pairs[j + 5], p6 = pairs[j + 6], p7 = pairs[j + 7];
        AGG_GATHER(p0, u0) AGG_GATHER(p1, u1) AGG_GATHER(p2, u2) AGG_GATHER(p3, u3)
        AGG_GATHER(p4, u4) AGG_GATHER(p5, u5) AGG_GATHER(p6, u6) AGG_GATHER(p7, u7)
        AGG_FMA(p0, u0) AGG_FMA(p1, u1) AGG_FMA(p2, u2) AGG_FMA(p3, u3)
        AGG_FMA(p4, u4) AGG_FMA(p5, u5) AGG_FMA(p6, u6) AGG_FMA(p7, u7)
    }
    for (; j + 1 < end; j += 2) {
        float2 p0 = pairs[j], p1 = pairs[j + 1];
        AGG_GATHER(p0, u0) AGG_GATHER(p1, u1)
        AGG_FMA(p0, u0) AGG_FMA(p1, u1)
    }
    if (j < end) {
        float2 p0 = pairs[j];
        AGG_GATHER(p0, u0)
        AGG_FMA(p0, u0)
    }
    return acc;
}

__global__ __launch_bounds__(256) void agg1_kernel(const int* __restrict__ rowptr,
                                                   const float2* __restrict__ pairs,
                                                   const uint* __restrict__ h0,
                                                   const float* __restrict__ b1,
                                                   float* __restrict__ h, int n) {
    const int lane = threadIdx.x & 63;
    const int node = blockIdx.x * 4 + (threadIdx.x >> 6);
    if (node >= n) return;
    float2 acc = agg_row(rowptr, pairs, h0, node, lane);
    float2 bb = *(const float2*)&b1[2 * lane];
    acc.x += bb.x;
    acc.y += bb.y;
    acc.x = acc.x > 0.f ? acc.x : expm1f(acc.x);
    acc.y = acc.y > 0.f ? acc.y : expm1f(acc.y);
    *(float2*)&h[(size_t)node * 128 + 2 * lane] = acc;
}

__global__ __launch_bounds__(256) void agg2_kernel(const int* __restrict__ rowptr,
                                                   const float2* __restrict__ pairs,
                                                   const uint* __restrict__ hcat,
                                                   const float* __restrict__ bmu,
                                                   const float* __restrict__ bls,
                                                   float* __restrict__ out, int n) {
    const int lane = threadIdx.x & 63;
    const int node = blockIdx.x * 4 + (threadIdx.x >> 6);
    if (node >= n) return;
    float2 acc = agg_row(rowptr, pairs, hcat, node, lane);
    const int ci = 2 * lane;
    if (lane < 32) {
        acc.x += bmu[ci];
        acc.y += bmu[ci + 1];
        *(float2*)&out[(size_t)node * 64 + ci] = acc;
    } else {
        acc.x += bls[ci - 64];
        acc.y += bls[ci - 63];
        *(float2*)&out[(size_t)n * 64 + (size_t)node * 64 + (ci - 64)] = acc;
    }
}

// ---------------------------------------------------------------------------

extern "C" void kernel_launch(void* const* d_in, const int* in_sizes, int n_in,
                              void* d_out, int out_size, void* d_ws, size_t ws_size,
                              hipStream_t stream) {
    const float* x   = (const float*)d_in[0];
    const int*   ei  = (const int*)d_in[1];
    const float* ew  = (const float*)d_in[2];
    const float* W1  = (const float*)d_in[3];
    const float* b1  = (const float*)d_in[4];
    const float* Wmu = (const float*)d_in[5];
    const float* bmu = (const float*)d_in[6];
    const float* Wls = (const float*)d_in[7];
    const float* bls = (const float*)d_in[8];
    float*       out = (float*)d_out;

    const int n = in_sizes[0] / IN_C;     // 50000
    const int e = in_sizes[2];            // 1600000
    const int nnz = e + n;
    const int nchunks = (nnz + CHUNK - 1) / CHUNK;
    const int gblocks = (n + 63) / 64;
    const unsigned bmag = (unsigned)(((unsigned long long)NB << 32) / (unsigned)n + 1);

    char* ws = (char*)d_ws;
    size_t off = 0;
    auto alloc = [&](size_t bytes) -> void* {
        void* p = ws + off;
        off = (off + bytes + 255) & ~(size_t)255;
        return p;
    };
    int*    hist   = (int*)   alloc((size_t)nchunks * NB * 4);
    int*    totals = (int*)   alloc(NB * 4);
    int*    bbase  = (int*)   alloc((NB + 1) * 4);
    int*    rowptr = (int*)   alloc((size_t)(n + 1) * 4);
    float*  dinv   = (float*) alloc((size_t)n * 4);
    float2* pairs  = (float2*)alloc((size_t)nnz * 8);
    float2* ptmp   = (float2*)alloc((size_t)nnz * 8);
    ushort* wt1_hi = (ushort*)alloc((size_t)128 * IN_C * 2);
    ushort* wt1_lo = (ushort*)alloc((size_t)128 * IN_C * 2);
    ushort* wt2_hi = (ushort*)alloc((size_t)128 * HID * 2);
    ushort* wt2_lo = (ushort*)alloc((size_t)128 * HID * 2);
    ushort* h0     = (ushort*)alloc((size_t)n * 128 * 2);   // bf16; hcat reuses
    ushort* hcat   = h0;                                    // dead after agg1
    (void)ws_size;
    float* hbuf = out;   // layer-1 activations (fp32) live in d_out

    prepA_kernel<<<nchunks + 192, 256, 0, stream>>>(ei, hist, e, n, bmag,
                                                    W1, Wmu, Wls,
                                                    wt1_hi, wt1_lo, wt2_hi, wt2_lo, nchunks);
    scanB1_kernel<<<NB, 256, 0, stream>>>(hist, totals, nchunks);
    scanB2_kernel<<<1, 256, 0, stream>>>(totals, bbase);
    gemm1_kernel<<<gblocks, 256, 0, stream>>>(x, wt1_hi, wt1_lo, h0, n);
    scatterC_kernel<<<nchunks, 256, 0, stream>>>(ei, ew, hist, bbase, ptmp, e, n, bmag);
    bucketD_kernel<<<NB, 256, 0, stream>>>(ptmp, bbase, pairs, rowptr, dinv, h0, n, nnz);
    agg1_kernel<<<(n + 3) / 4, 256, 0, stream>>>(rowptr, pairs, (const uint*)h0, b1, hbuf, n);
    gemm2_kernel<<<gblocks, 256, 0, stream>>>(hbuf, wt2_hi, wt2_lo, hcat, n, dinv);
    agg2_kernel<<<(n + 3) / 4, 256, 0, stream>>>(rowptr, pairs, (const uint*)hcat, bmu, bls, out, n);
}